// Round 4
// baseline (457.987 us; speedup 1.0000x reference)
//
#include <hip/hip_runtime.h>
#include <hip/hip_bf16.h>
#include <math.h>

typedef short  s16x8 __attribute__((ext_vector_type(8)));
typedef float  f32x4 __attribute__((ext_vector_type(4)));
typedef float  f32x2 __attribute__((ext_vector_type(2)));

#define LN_EPS 1e-6f

__device__ __forceinline__ unsigned short f2bf(float x) {
  union { float f; unsigned u; } v; v.f = x;
  unsigned r = v.u + 0x7FFFu + ((v.u >> 16) & 1u);  // RNE
  return (unsigned short)(r >> 16);
}
__device__ __forceinline__ float bf2f(unsigned short u) {
  union { unsigned u; float f; } v; v.u = ((unsigned)u) << 16;
  return v.f;
}
__device__ __forceinline__ float bflo(unsigned u) {
  union { unsigned u; float f; } v; v.u = u << 16; return v.f;
}
__device__ __forceinline__ float bfhi(unsigned u) {
  union { unsigned u; float f; } v; v.u = u & 0xFFFF0000u; return v.f;
}
__device__ __forceinline__ unsigned pack_bf2(float a, float b) {
  __hip_bfloat162 h = __float22bfloat162_rn(make_float2(a, b));
  unsigned u; __builtin_memcpy(&u, &h, 4); return u;
}
__device__ __forceinline__ float fast_tanh(float x) {
  float e = __expf(2.0f * x);
  return 1.0f - 2.0f * __builtin_amdgcn_rcpf(e + 1.0f);
}
__device__ __forceinline__ float fast_sigmoid(float x) {
  return __builtin_amdgcn_rcpf(1.0f + __expf(-x));
}

// ---- DPP reductions
template <int CTRL>
__device__ __forceinline__ float dpp_add(float v) {
  union { float f; int i; } a, r;
  a.f = v;
  r.i = __builtin_amdgcn_update_dpp(0, a.i, CTRL, 0xF, 0xF, true);
  return v + r.f;
}
template <int CTRL>
__device__ __forceinline__ float dpp_max(float v) {
  union { float f; int i; } a, r;
  a.f = v;
  r.i = __builtin_amdgcn_update_dpp(a.i, a.i, CTRL, 0xF, 0xF, false);
  return fmaxf(v, r.f);
}
__device__ __forceinline__ float bcast63(float v) {
  union { float f; int i; } a, r;
  a.f = v;
  r.i = __builtin_amdgcn_readlane(a.i, 63);
  return r.f;
}
// full-wave (64) sum / max
__device__ __forceinline__ float wredsum(float v) {
  v = dpp_add<0x128>(v); v = dpp_add<0x124>(v); v = dpp_add<0x122>(v); v = dpp_add<0x121>(v);
  v = dpp_add<0x142>(v); v = dpp_add<0x143>(v);
  return bcast63(v);
}
__device__ __forceinline__ float wredmax(float v) {
  v = dpp_max<0x128>(v); v = dpp_max<0x124>(v); v = dpp_max<0x122>(v); v = dpp_max<0x121>(v);
  v = dpp_max<0x142>(v); v = dpp_max<0x143>(v);
  return bcast63(v);
}
// 16-lane-row sum (result valid in all 16 lanes of the DPP row)
__device__ __forceinline__ float red16(float v) {
  v = dpp_add<0x121>(v); v = dpp_add<0x122>(v); v = dpp_add<0x124>(v); v = dpp_add<0x128>(v);
  return v;
}

__device__ __forceinline__ f32x4 mfma16(s16x8 a, s16x8 b, f32x4 c) {
  return __builtin_amdgcn_mfma_f32_16x16x32_bf16(a, b, c, 0, 0, 0);
}

// stage rows x 256 f32 -> bf16 into XOR-swizzled LDS ([row][k], byte ^= (row&7)<<4)
__device__ __forceinline__ void stage_rows(unsigned short* A, const float* src,
                                           int rows, int tid, int nthreads) {
  char* Ab = (char*)A;
  int nquads = rows * 64;
  #pragma unroll 4
  for (int p = tid; p < nquads; p += nthreads) {
    int row = p >> 6, kq = p & 63;
    f32x4 v = *(const f32x4*)(src + row * 256 + kq * 4);
    unsigned u0 = pack_bf2(v.x, v.y);
    unsigned u1 = pack_bf2(v.z, v.w);
    int byte = row * 512 + ((kq * 8) ^ ((row & 7) << 4));
    *(uint2*)(Ab + byte) = uint2{u0, u1};
  }
}

// A-frag: lane holds A[row][kk*32 + 8*hi + j], j=0..7
__device__ __forceinline__ s16x8 readA(const unsigned short* A, int row, int kk, int hi) {
  const char* Ab = (const char*)A;
  int byte = row * 512 + (((kk * 64) + hi * 16) ^ ((row & 7) << 4));
  return *(const s16x8*)(Ab + byte);
}
// B-frag from transposed bf16 weights Bt[N][256]
__device__ __forceinline__ s16x8 readB(const unsigned short* Bt, int col, int kk, int hi) {
  return *(const s16x8*)(Bt + col * 256 + kk * 32 + hi * 8);
}

// ---------------- K0: weight convert + transpose (coalesced 32x32 LDS tiles) ----------------
// bt_enc gets a column-pair permutation: position (w*32+l) holds real col (w*32+2l),
// position (w*32+16+l) holds real col (w*32+2l+1)  [so k_attn acc pairs are adjacent cols].
__global__ __launch_bounds__(256) void k_convw(
    const float* Win, const float* Wq, const float* Whid, const float* Wctx, const float* Wenc,
    unsigned short* bt_in, unsigned short* bt_q, unsigned short* bt_hid,
    unsigned short* bt_ctx, unsigned short* bt_enc) {
  __shared__ unsigned short tile[32][34];
  int b = blockIdx.x;
  const float* src; unsigned short* dst; int N, tk, tn; bool perm = false;
  if (b < 192) { src = Win; dst = bt_in; N = 768; tk = b & 7; tn = b >> 3; }
  else {
    int bb = b - 192; int m = bb >> 6; int r = bb & 63;
    tk = r & 7; tn = r >> 3; N = 256;
    src = (m == 0) ? Wq : (m == 1) ? Whid : (m == 2) ? Wctx : Wenc;
    dst = (m == 0) ? bt_q : (m == 1) ? bt_hid : (m == 2) ? bt_ctx : bt_enc;
    perm = (m == 3);
  }
  int k0 = tk * 32, n0 = tn * 32;
  {
    int i = threadIdx.x >> 3, j4 = (threadIdx.x & 7) * 4;
    f32x4 v = *(const f32x4*)(src + (size_t)(k0 + i) * N + n0 + j4);
    *(unsigned*)((char*)&tile[i][j4])     = pack_bf2(v.x, v.y);
    *(unsigned*)((char*)&tile[i][j4 + 2]) = pack_bf2(v.z, v.w);
  }
  __syncthreads();
  {
    int j = threadIdx.x >> 3, i4 = (threadIdx.x & 7) * 4;
    int c = n0 + j;
    int dr = perm ? ((c & ~31) | ((c & 31) >> 1) | ((c & 1) << 4)) : c;
    unsigned lo = (unsigned)tile[i4 + 0][j] | ((unsigned)tile[i4 + 1][j] << 16);
    unsigned hi = (unsigned)tile[i4 + 2][j] | ((unsigned)tile[i4 + 3][j] << 16);
    *(uint2*)(dst + (size_t)dr * 256 + k0 + i4) = uint2{lo, hi};
  }
}

// ---------------- K1: preact = LN(prev @ W_in) -> z,hg,xt ----------------
__global__ __launch_bounds__(256) void k_preact(
    const float* prev, const unsigned short* bt_in,
    const float* g_pre, const float* b_pre,
    float* Z, float* HG, float* XT) {
  __shared__ __align__(16) unsigned short A[16 * 256];
  __shared__ float C[16 * 768];
  int tid = threadIdx.x, lane = tid & 63, wave = tid >> 6;
  int hi = lane >> 4, lo = lane & 15;
  int r0 = blockIdx.x * 16;
  stage_rows(A, prev + (size_t)r0 * 256, 16, tid, 256);
  __syncthreads();
  f32x4 acc[12];
  #pragma unroll
  for (int ct = 0; ct < 12; ct++) acc[ct] = f32x4{0.f, 0.f, 0.f, 0.f};
  #pragma unroll
  for (int kk = 0; kk < 8; kk++) {
    s16x8 a = readA(A, lo, kk, hi);
    #pragma unroll
    for (int ct = 0; ct < 12; ct++) {
      s16x8 b = readB(bt_in, wave * 192 + ct * 16 + lo, kk, hi);
      acc[ct] = mfma16(a, b, acc[ct]);
    }
  }
  #pragma unroll
  for (int ct = 0; ct < 12; ct++) {
    int col = wave * 192 + ct * 16 + lo;
    #pragma unroll
    for (int r = 0; r < 4; r++) C[(hi * 4 + r) * 768 + col] = acc[ct][r];
  }
  __syncthreads();
  #pragma unroll
  for (int mm = 0; mm < 4; mm++) {
    int m = wave * 4 + mm;
    float x[12]; float s = 0.f, q = 0.f;
    #pragma unroll
    for (int i = 0; i < 12; i++) {
      x[i] = C[m * 768 + lane + 64 * i];
      s += x[i]; q += x[i] * x[i];
    }
    s = wredsum(s); q = wredsum(q);
    float mean = s * (1.0f / 768.0f);
    float var = q * (1.0f / 768.0f) - mean * mean;
    float rstd = rsqrtf(var + LN_EPS);
    int gr = r0 + m;
    #pragma unroll
    for (int i = 0; i < 12; i++) {
      int c = lane + 64 * i;
      float y = g_pre[c] * (x[i] - mean) * rstd + b_pre[c];
      if (c < 256)      Z [gr * 256 + c]         = fast_sigmoid(y);
      else if (c < 512) HG[gr * 256 + (c - 256)] = fast_sigmoid(y);
      else              XT[gr * 256 + (c - 512)] = y;
    }
  }
}

// ---------------- K2: SRU scan over T ----------------
__global__ __launch_bounds__(256) void k_scan(
    const float* hidden, const float* Z, const float* XT,
    float* SS, float* outFinalH) {
  int tid = blockIdx.x * 256 + threadIdx.x;  // 0..8191 == b*256+d
  float h = hidden[tid];
  for (int t0 = 0; t0 < 128; t0 += 8) {
    float zc[8], xc[8];
    #pragma unroll
    for (int j = 0; j < 8; j++) {
      zc[j] = Z [(t0 + j) * 8192 + tid];
      xc[j] = XT[(t0 + j) * 8192 + tid];
    }
    #pragma unroll
    for (int j = 0; j < 8; j++) {
      h = (1.0f - zc[j]) * h + zc[j] * xc[j];
      SS[(t0 + j) * 8192 + tid] = h;
    }
  }
  outFinalH[tid] = h;
}

// ---------------- K3: q = LN(ss @ W_q) ----------------
__global__ __launch_bounds__(256) void k_qproj(
    const float* SS, const unsigned short* bt_q,
    const float* g_q, const float* b_q, float* Q) {
  __shared__ __align__(16) unsigned short A[16 * 256];
  __shared__ float C[16 * 256];
  int tid = threadIdx.x, lane = tid & 63, wave = tid >> 6;
  int hi = lane >> 4, lo = lane & 15;
  int r0 = blockIdx.x * 16;
  stage_rows(A, SS + (size_t)r0 * 256, 16, tid, 256);
  __syncthreads();
  f32x4 acc[4];
  #pragma unroll
  for (int ct = 0; ct < 4; ct++) acc[ct] = f32x4{0.f, 0.f, 0.f, 0.f};
  #pragma unroll
  for (int kk = 0; kk < 8; kk++) {
    s16x8 a = readA(A, lo, kk, hi);
    #pragma unroll
    for (int ct = 0; ct < 4; ct++) {
      s16x8 b = readB(bt_q, wave * 64 + ct * 16 + lo, kk, hi);
      acc[ct] = mfma16(a, b, acc[ct]);
    }
  }
  #pragma unroll
  for (int ct = 0; ct < 4; ct++) {
    int col = wave * 64 + ct * 16 + lo;
    #pragma unroll
    for (int r = 0; r < 4; r++) C[(hi * 4 + r) * 256 + col] = acc[ct][r];
  }
  __syncthreads();
  #pragma unroll
  for (int mm = 0; mm < 4; mm++) {
    int m = wave * 4 + mm;
    float x[4]; float s = 0.f, q = 0.f;
    #pragma unroll
    for (int i = 0; i < 4; i++) {
      x[i] = C[m * 256 + lane + 64 * i];
      s += x[i]; q += x[i] * x[i];
    }
    s = wredsum(s); q = wredsum(q);
    float mean = s * (1.0f / 256.0f);
    float var = q * (1.0f / 256.0f) - mean * mean;
    float rstd = rsqrtf(var + LN_EPS);
    int gr = r0 + m;
    #pragma unroll
    for (int i = 0; i < 4; i++) {
      int c = lane + 64 * i;
      Q[gr * 256 + c] = g_q[c] * (x[i] - mean) * rstd + b_q[c];
    }
  }
}

// ---------------- K4: fused pctx GEMM + LN + MLP-attention (P in registers) ----------------
// acc[mt][0..1][r] = P[mt*16+hi*4+r][c0..c0+1], c0 = wave*32+2*lo  (bt_enc col-pair perm).
// LN fold: sum_s p_s*(g*(x_s-m_s)*r_s+b) = g*(sum_s a_s*x_s - beta)+b, a_s=p_s*r_s.
__global__ __launch_bounds__(512, 6) void k_attn(
    const float* enc, const unsigned short* bt_enc, const float* Q,
    const float* g_enc, const float* b_enc, const float* v_att,
    float* AOUT, float* attnOut) {
  __shared__ __align__(16) unsigned short AP[100 * 256];  // 51200 B: A staging; scratch after GEMM
  __shared__ __align__(16) float alpha[112];              // p_s * rstd_s (zero for s>=100)
  __shared__ __align__(16) f32x2 stats[112];              // {mean, rstd}
  __shared__ float beta_s;
  f32x2* statp = (f32x2*)AP;                      // [8][112] {sum, sumsq} per-wave partials
  float* spart = (float*)((char*)AP + 16384);     // [8][112] score partials
  int n = blockIdx.x;
  int tid = threadIdx.x, lane = tid & 63, wave = tid >> 6;
  int hi = lane >> 4, lo = lane & 15;
  // ---- stage enc row-block (exact trip: 12 full + 1 predicated tail)
  {
    const float* src = enc + (size_t)n * 25600;
    char* Ab = (char*)AP;
    #pragma unroll
    for (int i = 0; i < 12; i++) {
      int p = tid + i * 512;
      int row = p >> 6, kq = p & 63;
      f32x4 v = *(const f32x4*)(src + row * 256 + kq * 4);
      unsigned u0 = pack_bf2(v.x, v.y), u1 = pack_bf2(v.z, v.w);
      int byte = row * 512 + ((kq * 8) ^ ((row & 7) << 4));
      *(uint2*)(Ab + byte) = uint2{u0, u1};
    }
    if (tid < 256) {
      int p = 6144 + tid;
      int row = p >> 6, kq = p & 63;
      f32x4 v = *(const f32x4*)(src + row * 256 + kq * 4);
      unsigned u0 = pack_bf2(v.x, v.y), u1 = pack_bf2(v.z, v.w);
      int byte = row * 512 + ((kq * 8) ^ ((row & 7) << 4));
      *(uint2*)(Ab + byte) = uint2{u0, u1};
    }
  }
  __syncthreads();
  // ---- GEMM
  f32x4 acc[7][2];
  #pragma unroll
  for (int mt = 0; mt < 7; mt++) {
    acc[mt][0] = f32x4{0.f, 0.f, 0.f, 0.f};
    acc[mt][1] = f32x4{0.f, 0.f, 0.f, 0.f};
  }
  #pragma unroll
  for (int kk = 0; kk < 8; kk++) {
    s16x8 b0 = readB(bt_enc, wave * 32 + lo, kk, hi);
    s16x8 b1 = readB(bt_enc, wave * 32 + 16 + lo, kk, hi);
    #pragma unroll
    for (int mt = 0; mt < 7; mt++) {
      int ar = mt * 16 + lo;
      ar = ar > 99 ? 99 : ar;   // ragged mt=6: rows>=100 read row 99, results discarded
      s16x8 a = readA(AP, ar, kk, hi);
      acc[mt][0] = mfma16(a, b0, acc[mt][0]);
      acc[mt][1] = mfma16(a, b1, acc[mt][1]);
    }
  }
  __syncthreads();   // A staging dead; AP becomes partial-scratch
  // ---- pack to bf16 regs + per-wave row stats (sum, sumsq over this wave's 32 cols)
  unsigned pk[7][4];
  #pragma unroll
  for (int mt = 0; mt < 7; mt++) {
    #pragma unroll
    for (int r = 0; r < 4; r++) {
      unsigned u = pack_bf2(acc[mt][0][r], acc[mt][1][r]);
      pk[mt][r] = u;
      float x0 = bflo(u), x1 = bfhi(u);
      float s = red16(x0 + x1);
      float q = red16(fmaf(x0, x0, x1 * x1));
      if (lo == 0) statp[wave * 112 + mt * 16 + hi * 4 + r] = f32x2{s, q};
    }
  }
  __syncthreads();
  // ---- combine row stats
  if (tid < 112) {
    float S = 0.f, Qs = 0.f;
    #pragma unroll
    for (int w = 0; w < 8; w++) {
      f32x2 t = statp[w * 112 + tid];
      S += t.x; Qs += t.y;
    }
    float mean = S * (1.0f / 256.0f);
    float var = Qs * (1.0f / 256.0f) - mean * mean;
    stats[tid] = f32x2{mean, rsqrtf(var + LN_EPS)};
  }
  __syncthreads();
  // ---- register scores: t = v0*tanh(q0+LN0) + v1*tanh(q1+LN1), reduce over 16 lanes
  int c0 = (wave << 5) + (lo << 1);
  f32x2 gp = *(const f32x2*)(g_enc + c0);
  f32x2 bp = *(const f32x2*)(b_enc + c0);
  f32x2 vp = *(const f32x2*)(v_att + c0);
  f32x2 qp = *(const f32x2*)(Q + (size_t)n * 256 + c0);
  #pragma unroll
  for (int mt = 0; mt < 7; mt++) {
    #pragma unroll
    for (int r = 0; r < 4; r++) {
      int row = mt * 16 + hi * 4 + r;
      f32x2 st = stats[row];
      float x0 = bflo(pk[mt][r]), x1 = bfhi(pk[mt][r]);
      float t = vp.x * fast_tanh(qp.x + fmaf(gp.x, (x0 - st.x) * st.y, bp.x))
              + vp.y * fast_tanh(qp.y + fmaf(gp.y, (x1 - st.x) * st.y, bp.y));
      t = red16(t);
      if (lo == 0) spart[wave * 112 + row] = t;
    }
  }
  __syncthreads();
  // ---- softmax + alpha/beta (wave 0)
  if (wave == 0) {
    int row2 = (lane < 36) ? lane + 64 : lane;
    float s1 = 0.f, s2 = 0.f;
    #pragma unroll
    for (int w = 0; w < 8; w++) {
      s1 += spart[w * 112 + lane];
      s2 += spart[w * 112 + row2];
    }
    s2 = (lane < 36) ? s2 : -INFINITY;
    float mx = wredmax(fmaxf(s1, s2));
    float e1 = __expf(s1 - mx);
    float e2 = (lane < 36) ? __expf(s2 - mx) : 0.f;
    float sm = wredsum(e1 + e2);
    float inv = __builtin_amdgcn_rcpf(sm);
    float p1 = e1 * inv, p2 = e2 * inv;
    f32x2 st1 = stats[lane];
    float a1 = p1 * st1.y, bsum = a1 * st1.x;
    float a2 = 0.f;
    if (lane < 36) {
      f32x2 st2 = stats[lane + 64];
      a2 = p2 * st2.y; bsum = fmaf(a2, st2.x, bsum);
    }
    alpha[lane] = a1;
    if (lane < 48) alpha[lane + 64] = a2;   // rows 100..111 get 0
    float bp_ = wredsum(bsum);
    if (lane == 0) beta_s = bp_;
    attnOut[(size_t)n * 100 + lane] = p1;
    if (lane < 36) attnOut[(size_t)n * 100 + lane + 64] = p2;
  }
  __syncthreads();
  // ---- weighted sum from registers: w = sum_s alpha[s] * P[s][c]
  float w0 = 0.f, w1 = 0.f;
  #pragma unroll
  for (int mt = 0; mt < 7; mt++) {
    f32x4 al = *(const f32x4*)(alpha + mt * 16 + hi * 4);
    #pragma unroll
    for (int r = 0; r < 4; r++) {
      w0 = fmaf(al[r], bflo(pk[mt][r]), w0);
      w1 = fmaf(al[r], bfhi(pk[mt][r]), w1);
    }
  }
  w0 += __shfl_xor(w0, 16); w0 += __shfl_xor(w0, 32);
  w1 += __shfl_xor(w1, 16); w1 += __shfl_xor(w1, 32);
  if (lane < 16) {
    float y0 = fmaf(gp.x, w0 - beta_s, bp.x) * 0.0625f;
    float y1 = fmaf(gp.y, w1 - beta_s, bp.y) * 0.0625f;
    *(f32x2*)(AOUT + (size_t)n * 256 + c0) = f32x2{y0, y1};
  }
}

// ---------------- K5: out = highway(tanh(LN(ss@W_hid)+LN(aout@W_ctx))) ----------------
__global__ __launch_bounds__(256) void k_out(
    const float* SS, const float* AOUT,
    const unsigned short* bt_hid, const unsigned short* bt_ctx,
    const float* g_h, const float* b_h, const float* g_c, const float* b_c,
    const float* HG, const float* prev, float* out) {
  __shared__ __align__(16) unsigned short A1[16 * 256];
  __shared__ __align__(16) unsigned short A2[16 * 256];
  __shared__ float C1[16 * 256];
  __shared__ float C2[16 * 256];
  int tid = threadIdx.x, lane = tid & 63, wave = tid >> 6;
  int hi = lane >> 4, lo = lane & 15;
  int r0 = blockIdx.x * 16;
  stage_rows(A1, SS + (size_t)r0 * 256, 16, tid, 256);
  stage_rows(A2, AOUT + (size_t)r0 * 256, 16, tid, 256);
  __syncthreads();
  f32x4 acc1[4], acc2[4];
  #pragma unroll
  for (int ct = 0; ct < 4; ct++) {
    acc1[ct] = f32x4{0.f, 0.f, 0.f, 0.f};
    acc2[ct] = f32x4{0.f, 0.f, 0.f, 0.f};
  }
  #pragma unroll
  for (int kk = 0; kk < 8; kk++) {
    s16x8 a1 = readA(A1, lo, kk, hi);
    s16x8 a2 = readA(A2, lo, kk, hi);
    #pragma unroll
    for (int ct = 0; ct < 4; ct++) {
      int col = wave * 64 + ct * 16 + lo;
      s16x8 b1 = readB(bt_hid, col, kk, hi);
      s16x8 b2 = readB(bt_ctx, col, kk, hi);
      acc1[ct] = mfma16(a1, b1, acc1[ct]);
      acc2[ct] = mfma16(a2, b2, acc2[ct]);
    }
  }
  #pragma unroll
  for (int ct = 0; ct < 4; ct++) {
    int col = wave * 64 + ct * 16 + lo;
    #pragma unroll
    for (int r = 0; r < 4; r++) {
      C1[(hi * 4 + r) * 256 + col] = acc1[ct][r];
      C2[(hi * 4 + r) * 256 + col] = acc2[ct][r];
    }
  }
  __syncthreads();
  #pragma unroll
  for (int mm = 0; mm < 4; mm++) {
    int m = wave * 4 + mm;
    float x1[4], x2[4];
    float s1 = 0.f, q1 = 0.f, s2 = 0.f, q2 = 0.f;
    #pragma unroll
    for (int i = 0; i < 4; i++) {
      x1[i] = C1[m * 256 + lane + 64 * i];
      x2[i] = C2[m * 256 + lane + 64 * i];
      s1 += x1[i]; q1 += x1[i] * x1[i];
      s2 += x2[i]; q2 += x2[i] * x2[i];
    }
    s1 = wredsum(s1); q1 = wredsum(q1);
    s2 = wredsum(s2); q2 = wredsum(q2);
    float mean1 = s1 * (1.0f / 256.0f), var1 = q1 * (1.0f / 256.0f) - mean1 * mean1;
    float mean2 = s2 * (1.0f / 256.0f), var2 = q2 * (1.0f / 256.0f) - mean2 * mean2;
    float rstd1 = rsqrtf(var1 + LN_EPS), rstd2 = rsqrtf(var2 + LN_EPS);
    int gr = r0 + m;
    #pragma unroll
    for (int i = 0; i < 4; i++) {
      int c = lane + 64 * i;
      float y1 = g_h[c] * (x1[i] - mean1) * rstd1 + b_h[c];
      float y2 = g_c[c] * (x2[i] - mean2) * rstd2 + b_c[c];
      float y = fast_tanh(y1 + y2);
      float g = HG[gr * 256 + c];
      float pv = prev[gr * 256 + c];
      out[gr * 256 + c] = (1.0f - g) * y + g * pv;
    }
  }
}

extern "C" void kernel_launch(void* const* d_in, const int* in_sizes, int n_in,
                              void* d_out, int out_size, void* d_ws, size_t ws_size,
                              hipStream_t stream) {
  const float* prev   = (const float*)d_in[0];
  const float* hidden = (const float*)d_in[1];
  const float* enc    = (const float*)d_in[2];
  const float* W_in   = (const float*)d_in[3];
  const float* W_hid  = (const float*)d_in[4];
  const float* W_ctx  = (const float*)d_in[5];
  const float* W_enc  = (const float*)d_in[6];
  const float* W_q    = (const float*)d_in[7];
  const float* v_att  = (const float*)d_in[8];
  const float* g_pre  = (const float*)d_in[9];
  const float* b_pre  = (const float*)d_in[10];
  const float* g_enc  = (const float*)d_in[11];
  const float* b_enc  = (const float*)d_in[12];
  const float* g_h    = (const float*)d_in[13];
  const float* b_h    = (const float*)d_in[14];
  const float* g_c    = (const float*)d_in[15];
  const float* b_c    = (const float*)d_in[16];
  const float* g_q    = (const float*)d_in[17];
  const float* b_q    = (const float*)d_in[18];

  char* ws = (char*)d_ws;
  unsigned short* BT_IN  = (unsigned short*)(ws + 0);        // 768x256 bf16
  unsigned short* BT_Q   = (unsigned short*)(ws + 393216);
  unsigned short* BT_HID = (unsigned short*)(ws + 524288);
  unsigned short* BT_CTX = (unsigned short*)(ws + 655360);
  unsigned short* BT_ENC = (unsigned short*)(ws + 786432);
  float* Z    = (float*)(ws + 917504);    // [4096][256]
  float* HG   = (float*)(ws + 5111808);
  float* XT   = (float*)(ws + 9306112);
  float* SS   = (float*)(ws + 13500416);
  float* Q    = (float*)(ws + 17694720);
  float* AOUT = (float*)(ws + 21889024);

  float* out    = (float*)d_out;          // [4096][256]
  float* finalH = out + 1048576;          // [32][256]
  float* attnO  = out + 1056768;          // [4096][100]

  k_convw <<<448, 256, 0, stream>>>(W_in, W_q, W_hid, W_ctx, W_enc,
                                    BT_IN, BT_Q, BT_HID, BT_CTX, BT_ENC);
  k_preact<<<256, 256, 0, stream>>>(prev, BT_IN, g_pre, b_pre, Z, HG, XT);
  k_scan  <<<32, 256, 0, stream>>>(hidden, Z, XT, SS, finalH);
  k_qproj <<<256, 256, 0, stream>>>(SS, BT_Q, g_q, b_q, Q);
  k_attn  <<<4096, 512, 0, stream>>>(enc, BT_ENC, Q, g_enc, b_enc, v_att, AOUT, attnO);
  k_out   <<<256, 256, 0, stream>>>(SS, AOUT, BT_HID, BT_CTX,
                                    g_h, b_h, g_c, b_c, HG, prev, out);
}

// Round 5
// 267.986 us; speedup vs baseline: 1.7090x; 1.7090x over previous
//
#include <hip/hip_runtime.h>
#include <hip/hip_bf16.h>
#include <math.h>

typedef short  s16x8 __attribute__((ext_vector_type(8)));
typedef float  f32x4 __attribute__((ext_vector_type(4)));
typedef float  f32x2 __attribute__((ext_vector_type(2)));

#define LN_EPS 1e-6f

__device__ __forceinline__ unsigned short f2bf(float x) {
  union { float f; unsigned u; } v; v.f = x;
  unsigned r = v.u + 0x7FFFu + ((v.u >> 16) & 1u);  // RNE
  return (unsigned short)(r >> 16);
}
__device__ __forceinline__ float bf2f(unsigned short u) {
  union { unsigned u; float f; } v; v.u = ((unsigned)u) << 16;
  return v.f;
}
__device__ __forceinline__ float bflo(unsigned u) {
  union { unsigned u; float f; } v; v.u = u << 16; return v.f;
}
__device__ __forceinline__ float bfhi(unsigned u) {
  union { unsigned u; float f; } v; v.u = u & 0xFFFF0000u; return v.f;
}
__device__ __forceinline__ unsigned pack_bf2(float a, float b) {
  __hip_bfloat162 h = __float22bfloat162_rn(make_float2(a, b));
  unsigned u; __builtin_memcpy(&u, &h, 4); return u;
}
__device__ __forceinline__ float fast_tanh(float x) {
  float e = __expf(2.0f * x);
  return 1.0f - 2.0f * __builtin_amdgcn_rcpf(e + 1.0f);
}
__device__ __forceinline__ float fast_sigmoid(float x) {
  return __builtin_amdgcn_rcpf(1.0f + __expf(-x));
}

// ---- DPP reductions
template <int CTRL>
__device__ __forceinline__ float dpp_add(float v) {
  union { float f; int i; } a, r;
  a.f = v;
  r.i = __builtin_amdgcn_update_dpp(0, a.i, CTRL, 0xF, 0xF, true);
  return v + r.f;
}
template <int CTRL>
__device__ __forceinline__ float dpp_max(float v) {
  union { float f; int i; } a, r;
  a.f = v;
  r.i = __builtin_amdgcn_update_dpp(a.i, a.i, CTRL, 0xF, 0xF, false);
  return fmaxf(v, r.f);
}
__device__ __forceinline__ float bcast63(float v) {
  union { float f; int i; } a, r;
  a.f = v;
  r.i = __builtin_amdgcn_readlane(a.i, 63);
  return r.f;
}
// full-wave (64) sum / max
__device__ __forceinline__ float wredsum(float v) {
  v = dpp_add<0x128>(v); v = dpp_add<0x124>(v); v = dpp_add<0x122>(v); v = dpp_add<0x121>(v);
  v = dpp_add<0x142>(v); v = dpp_add<0x143>(v);
  return bcast63(v);
}
__device__ __forceinline__ float wredmax(float v) {
  v = dpp_max<0x128>(v); v = dpp_max<0x124>(v); v = dpp_max<0x122>(v); v = dpp_max<0x121>(v);
  v = dpp_max<0x142>(v); v = dpp_max<0x143>(v);
  return bcast63(v);
}
// 16-lane-row sum (result valid in all 16 lanes of the DPP row)
__device__ __forceinline__ float red16(float v) {
  v = dpp_add<0x121>(v); v = dpp_add<0x122>(v); v = dpp_add<0x124>(v); v = dpp_add<0x128>(v);
  return v;
}

__device__ __forceinline__ f32x4 mfma16(s16x8 a, s16x8 b, f32x4 c) {
  return __builtin_amdgcn_mfma_f32_16x16x32_bf16(a, b, c, 0, 0, 0);
}

// stage rows x 256 f32 -> bf16 into XOR-swizzled LDS ([row][k], byte ^= (row&7)<<4)
__device__ __forceinline__ void stage_rows(unsigned short* A, const float* src,
                                           int rows, int tid, int nthreads) {
  char* Ab = (char*)A;
  int nquads = rows * 64;
  #pragma unroll 4
  for (int p = tid; p < nquads; p += nthreads) {
    int row = p >> 6, kq = p & 63;
    f32x4 v = *(const f32x4*)(src + row * 256 + kq * 4);
    unsigned u0 = pack_bf2(v.x, v.y);
    unsigned u1 = pack_bf2(v.z, v.w);
    int byte = row * 512 + ((kq * 8) ^ ((row & 7) << 4));
    *(uint2*)(Ab + byte) = uint2{u0, u1};
  }
}

// A-frag: lane holds A[row][kk*32 + 8*hi + j], j=0..7
__device__ __forceinline__ s16x8 readA(const unsigned short* A, int row, int kk, int hi) {
  const char* Ab = (const char*)A;
  int byte = row * 512 + (((kk * 64) + hi * 16) ^ ((row & 7) << 4));
  return *(const s16x8*)(Ab + byte);
}
// B-frag from transposed bf16 weights Bt[N][256]
__device__ __forceinline__ s16x8 readB(const unsigned short* Bt, int col, int kk, int hi) {
  return *(const s16x8*)(Bt + col * 256 + kk * 32 + hi * 8);
}

// ---------------- K0: weight convert + transpose (coalesced 32x32 LDS tiles) ----------------
// bt_enc gets a column-pair permutation: position (w*32+l) holds real col (w*32+2l),
// position (w*32+16+l) holds real col (w*32+2l+1)  [so k_attn acc pairs are adjacent cols].
__global__ __launch_bounds__(256) void k_convw(
    const float* Win, const float* Wq, const float* Whid, const float* Wctx, const float* Wenc,
    unsigned short* bt_in, unsigned short* bt_q, unsigned short* bt_hid,
    unsigned short* bt_ctx, unsigned short* bt_enc) {
  __shared__ unsigned short tile[32][34];
  int b = blockIdx.x;
  const float* src; unsigned short* dst; int N, tk, tn; bool perm = false;
  if (b < 192) { src = Win; dst = bt_in; N = 768; tk = b & 7; tn = b >> 3; }
  else {
    int bb = b - 192; int m = bb >> 6; int r = bb & 63;
    tk = r & 7; tn = r >> 3; N = 256;
    src = (m == 0) ? Wq : (m == 1) ? Whid : (m == 2) ? Wctx : Wenc;
    dst = (m == 0) ? bt_q : (m == 1) ? bt_hid : (m == 2) ? bt_ctx : bt_enc;
    perm = (m == 3);
  }
  int k0 = tk * 32, n0 = tn * 32;
  {
    int i = threadIdx.x >> 3, j4 = (threadIdx.x & 7) * 4;
    f32x4 v = *(const f32x4*)(src + (size_t)(k0 + i) * N + n0 + j4);
    *(unsigned*)((char*)&tile[i][j4])     = pack_bf2(v.x, v.y);
    *(unsigned*)((char*)&tile[i][j4 + 2]) = pack_bf2(v.z, v.w);
  }
  __syncthreads();
  {
    int j = threadIdx.x >> 3, i4 = (threadIdx.x & 7) * 4;
    int c = n0 + j;
    int dr = perm ? ((c & ~31) | ((c & 31) >> 1) | ((c & 1) << 4)) : c;
    unsigned lo = (unsigned)tile[i4 + 0][j] | ((unsigned)tile[i4 + 1][j] << 16);
    unsigned hi = (unsigned)tile[i4 + 2][j] | ((unsigned)tile[i4 + 3][j] << 16);
    *(uint2*)(dst + (size_t)dr * 256 + k0 + i4) = uint2{lo, hi};
  }
}

// ---------------- K1: preact = LN(prev @ W_in) -> z,hg,xt ----------------
__global__ __launch_bounds__(256) void k_preact(
    const float* prev, const unsigned short* bt_in,
    const float* g_pre, const float* b_pre,
    float* Z, float* HG, float* XT) {
  __shared__ __align__(16) unsigned short A[16 * 256];
  __shared__ float C[16 * 768];
  int tid = threadIdx.x, lane = tid & 63, wave = tid >> 6;
  int hi = lane >> 4, lo = lane & 15;
  int r0 = blockIdx.x * 16;
  stage_rows(A, prev + (size_t)r0 * 256, 16, tid, 256);
  __syncthreads();
  f32x4 acc[12];
  #pragma unroll
  for (int ct = 0; ct < 12; ct++) acc[ct] = f32x4{0.f, 0.f, 0.f, 0.f};
  #pragma unroll
  for (int kk = 0; kk < 8; kk++) {
    s16x8 a = readA(A, lo, kk, hi);
    #pragma unroll
    for (int ct = 0; ct < 12; ct++) {
      s16x8 b = readB(bt_in, wave * 192 + ct * 16 + lo, kk, hi);
      acc[ct] = mfma16(a, b, acc[ct]);
    }
  }
  #pragma unroll
  for (int ct = 0; ct < 12; ct++) {
    int col = wave * 192 + ct * 16 + lo;
    #pragma unroll
    for (int r = 0; r < 4; r++) C[(hi * 4 + r) * 768 + col] = acc[ct][r];
  }
  __syncthreads();
  #pragma unroll
  for (int mm = 0; mm < 4; mm++) {
    int m = wave * 4 + mm;
    float x[12]; float s = 0.f, q = 0.f;
    #pragma unroll
    for (int i = 0; i < 12; i++) {
      x[i] = C[m * 768 + lane + 64 * i];
      s += x[i]; q += x[i] * x[i];
    }
    s = wredsum(s); q = wredsum(q);
    float mean = s * (1.0f / 768.0f);
    float var = q * (1.0f / 768.0f) - mean * mean;
    float rstd = rsqrtf(var + LN_EPS);
    int gr = r0 + m;
    #pragma unroll
    for (int i = 0; i < 12; i++) {
      int c = lane + 64 * i;
      float y = g_pre[c] * (x[i] - mean) * rstd + b_pre[c];
      if (c < 256)      Z [gr * 256 + c]         = fast_sigmoid(y);
      else if (c < 512) HG[gr * 256 + (c - 256)] = fast_sigmoid(y);
      else              XT[gr * 256 + (c - 512)] = y;
    }
  }
}

// ---------------- K2: SRU scan over T ----------------
__global__ __launch_bounds__(256) void k_scan(
    const float* hidden, const float* Z, const float* XT,
    float* SS, float* outFinalH) {
  int tid = blockIdx.x * 256 + threadIdx.x;  // 0..8191 == b*256+d
  float h = hidden[tid];
  for (int t0 = 0; t0 < 128; t0 += 8) {
    float zc[8], xc[8];
    #pragma unroll
    for (int j = 0; j < 8; j++) {
      zc[j] = Z [(t0 + j) * 8192 + tid];
      xc[j] = XT[(t0 + j) * 8192 + tid];
    }
    #pragma unroll
    for (int j = 0; j < 8; j++) {
      h = (1.0f - zc[j]) * h + zc[j] * xc[j];
      SS[(t0 + j) * 8192 + tid] = h;
    }
  }
  outFinalH[tid] = h;
}

// ---------------- K3: q = LN(ss @ W_q) ----------------
__global__ __launch_bounds__(256) void k_qproj(
    const float* SS, const unsigned short* bt_q,
    const float* g_q, const float* b_q, float* Q) {
  __shared__ __align__(16) unsigned short A[16 * 256];
  __shared__ float C[16 * 256];
  int tid = threadIdx.x, lane = tid & 63, wave = tid >> 6;
  int hi = lane >> 4, lo = lane & 15;
  int r0 = blockIdx.x * 16;
  stage_rows(A, SS + (size_t)r0 * 256, 16, tid, 256);
  __syncthreads();
  f32x4 acc[4];
  #pragma unroll
  for (int ct = 0; ct < 4; ct++) acc[ct] = f32x4{0.f, 0.f, 0.f, 0.f};
  #pragma unroll
  for (int kk = 0; kk < 8; kk++) {
    s16x8 a = readA(A, lo, kk, hi);
    #pragma unroll
    for (int ct = 0; ct < 4; ct++) {
      s16x8 b = readB(bt_q, wave * 64 + ct * 16 + lo, kk, hi);
      acc[ct] = mfma16(a, b, acc[ct]);
    }
  }
  #pragma unroll
  for (int ct = 0; ct < 4; ct++) {
    int col = wave * 64 + ct * 16 + lo;
    #pragma unroll
    for (int r = 0; r < 4; r++) C[(hi * 4 + r) * 256 + col] = acc[ct][r];
  }
  __syncthreads();
  #pragma unroll
  for (int mm = 0; mm < 4; mm++) {
    int m = wave * 4 + mm;
    float x[4]; float s = 0.f, q = 0.f;
    #pragma unroll
    for (int i = 0; i < 4; i++) {
      x[i] = C[m * 256 + lane + 64 * i];
      s += x[i]; q += x[i] * x[i];
    }
    s = wredsum(s); q = wredsum(q);
    float mean = s * (1.0f / 256.0f);
    float var = q * (1.0f / 256.0f) - mean * mean;
    float rstd = rsqrtf(var + LN_EPS);
    int gr = r0 + m;
    #pragma unroll
    for (int i = 0; i < 4; i++) {
      int c = lane + 64 * i;
      Q[gr * 256 + c] = g_q[c] * (x[i] - mean) * rstd + b_q[c];
    }
  }
}

// ---------------- K4: fused pctx GEMM + LN + MLP-attention (P in registers) ----------------
// acc[mt][0..1][r] = P[mt*16+hi*4+r][c0..c0+1], c0 = wave*32+2*lo  (bt_enc col-pair perm).
// LN fold: sum_s p_s*(g*(x_s-m_s)*r_s+b) = g*(sum_s a_s*x_s - beta)+b, a_s=p_s*r_s.
// launch_bounds (512,4): <=128 VGPR so the pk[7][4]+acc live set does NOT spill.
__global__ __launch_bounds__(512, 4) void k_attn(
    const float* enc, const unsigned short* bt_enc, const float* Q,
    const float* g_enc, const float* b_enc, const float* v_att,
    float* AOUT, float* attnOut) {
  __shared__ __align__(16) unsigned short AP[100 * 256];  // 51200 B: A staging; scratch after GEMM
  __shared__ __align__(16) float alpha[112];              // p_s * rstd_s (zero for s>=100)
  __shared__ __align__(16) f32x2 stats[112];              // {mean, rstd}
  __shared__ float beta_s;
  f32x2* statp = (f32x2*)AP;                      // [8][112] {sum, sumsq} per-wave partials
  float* spart = (float*)((char*)AP + 16384);     // [8][112] score partials
  int n = blockIdx.x;
  int tid = threadIdx.x, lane = tid & 63, wave = tid >> 6;
  int hi = lane >> 4, lo = lane & 15;
  // ---- stage enc row-block (exact trip: 12 full + 1 predicated tail)
  {
    const float* src = enc + (size_t)n * 25600;
    char* Ab = (char*)AP;
    #pragma unroll
    for (int i = 0; i < 12; i++) {
      int p = tid + i * 512;
      int row = p >> 6, kq = p & 63;
      f32x4 v = *(const f32x4*)(src + row * 256 + kq * 4);
      unsigned u0 = pack_bf2(v.x, v.y), u1 = pack_bf2(v.z, v.w);
      int byte = row * 512 + ((kq * 8) ^ ((row & 7) << 4));
      *(uint2*)(Ab + byte) = uint2{u0, u1};
    }
    if (tid < 256) {
      int p = 6144 + tid;
      int row = p >> 6, kq = p & 63;
      f32x4 v = *(const f32x4*)(src + row * 256 + kq * 4);
      unsigned u0 = pack_bf2(v.x, v.y), u1 = pack_bf2(v.z, v.w);
      int byte = row * 512 + ((kq * 8) ^ ((row & 7) << 4));
      *(uint2*)(Ab + byte) = uint2{u0, u1};
    }
  }
  __syncthreads();
  // ---- GEMM
  f32x4 acc[7][2];
  #pragma unroll
  for (int mt = 0; mt < 7; mt++) {
    acc[mt][0] = f32x4{0.f, 0.f, 0.f, 0.f};
    acc[mt][1] = f32x4{0.f, 0.f, 0.f, 0.f};
  }
  #pragma unroll
  for (int kk = 0; kk < 8; kk++) {
    s16x8 b0 = readB(bt_enc, wave * 32 + lo, kk, hi);
    s16x8 b1 = readB(bt_enc, wave * 32 + 16 + lo, kk, hi);
    #pragma unroll
    for (int mt = 0; mt < 7; mt++) {
      int ar = mt * 16 + lo;
      ar = ar > 99 ? 99 : ar;   // ragged mt=6: rows>=100 read row 99, results discarded
      s16x8 a = readA(AP, ar, kk, hi);
      acc[mt][0] = mfma16(a, b0, acc[mt][0]);
      acc[mt][1] = mfma16(a, b1, acc[mt][1]);
    }
  }
  __syncthreads();   // A staging dead; AP becomes partial-scratch
  // ---- pack to bf16 regs + per-wave row stats (sum, sumsq over this wave's 32 cols)
  unsigned pk[7][4];
  #pragma unroll
  for (int mt = 0; mt < 7; mt++) {
    #pragma unroll
    for (int r = 0; r < 4; r++) {
      unsigned u = pack_bf2(acc[mt][0][r], acc[mt][1][r]);
      pk[mt][r] = u;
      float x0 = bflo(u), x1 = bfhi(u);
      float s = red16(x0 + x1);
      float q = red16(fmaf(x0, x0, x1 * x1));
      if (lo == 0) statp[wave * 112 + mt * 16 + hi * 4 + r] = f32x2{s, q};
    }
  }
  __syncthreads();
  // ---- combine row stats
  if (tid < 112) {
    float S = 0.f, Qs = 0.f;
    #pragma unroll
    for (int w = 0; w < 8; w++) {
      f32x2 t = statp[w * 112 + tid];
      S += t.x; Qs += t.y;
    }
    float mean = S * (1.0f / 256.0f);
    float var = Qs * (1.0f / 256.0f) - mean * mean;
    stats[tid] = f32x2{mean, rsqrtf(var + LN_EPS)};
  }
  __syncthreads();
  // ---- register scores: t = v0*tanh(q0+LN0) + v1*tanh(q1+LN1), reduce over 16 lanes
  int c0 = (wave << 5) + (lo << 1);
  f32x2 gp = *(const f32x2*)(g_enc + c0);
  f32x2 bp = *(const f32x2*)(b_enc + c0);
  f32x2 vp = *(const f32x2*)(v_att + c0);
  f32x2 qp = *(const f32x2*)(Q + (size_t)n * 256 + c0);
  #pragma unroll
  for (int mt = 0; mt < 7; mt++) {
    #pragma unroll
    for (int r = 0; r < 4; r++) {
      int row = mt * 16 + hi * 4 + r;
      f32x2 st = stats[row];
      float x0 = bflo(pk[mt][r]), x1 = bfhi(pk[mt][r]);
      float t = vp.x * fast_tanh(qp.x + fmaf(gp.x, (x0 - st.x) * st.y, bp.x))
              + vp.y * fast_tanh(qp.y + fmaf(gp.y, (x1 - st.x) * st.y, bp.y));
      t = red16(t);
      if (lo == 0) spart[wave * 112 + row] = t;
    }
  }
  __syncthreads();
  // ---- softmax + alpha/beta (wave 0)
  if (wave == 0) {
    int row2 = (lane < 36) ? lane + 64 : lane;
    float s1 = 0.f, s2 = 0.f;
    #pragma unroll
    for (int w = 0; w < 8; w++) {
      s1 += spart[w * 112 + lane];
      s2 += spart[w * 112 + row2];
    }
    s2 = (lane < 36) ? s2 : -INFINITY;
    float mx = wredmax(fmaxf(s1, s2));
    float e1 = __expf(s1 - mx);
    float e2 = (lane < 36) ? __expf(s2 - mx) : 0.f;
    float sm = wredsum(e1 + e2);
    float inv = __builtin_amdgcn_rcpf(sm);
    float p1 = e1 * inv, p2 = e2 * inv;
    f32x2 st1 = stats[lane];
    float a1 = p1 * st1.y, bsum = a1 * st1.x;
    float a2 = 0.f;
    if (lane < 36) {
      f32x2 st2 = stats[lane + 64];
      a2 = p2 * st2.y; bsum = fmaf(a2, st2.x, bsum);
    }
    alpha[lane] = a1;
    if (lane < 48) alpha[lane + 64] = a2;   // rows 100..111 get 0
    float bp_ = wredsum(bsum);
    if (lane == 0) beta_s = bp_;
    attnOut[(size_t)n * 100 + lane] = p1;
    if (lane < 36) attnOut[(size_t)n * 100 + lane + 64] = p2;
  }
  __syncthreads();
  // ---- weighted sum from registers: w = sum_s alpha[s] * P[s][c]
  float w0 = 0.f, w1 = 0.f;
  #pragma unroll
  for (int mt = 0; mt < 7; mt++) {
    f32x4 al = *(const f32x4*)(alpha + mt * 16 + hi * 4);
    #pragma unroll
    for (int r = 0; r < 4; r++) {
      w0 = fmaf(al[r], bflo(pk[mt][r]), w0);
      w1 = fmaf(al[r], bfhi(pk[mt][r]), w1);
    }
  }
  w0 += __shfl_xor(w0, 16); w0 += __shfl_xor(w0, 32);
  w1 += __shfl_xor(w1, 16); w1 += __shfl_xor(w1, 32);
  if (lane < 16) {
    float y0 = fmaf(gp.x, w0 - beta_s, bp.x) * 0.0625f;
    float y1 = fmaf(gp.y, w1 - beta_s, bp.y) * 0.0625f;
    *(f32x2*)(AOUT + (size_t)n * 256 + c0) = f32x2{y0, y1};
  }
}

// ---------------- K5: out = highway(tanh(LN(ss@W_hid)+LN(aout@W_ctx))) ----------------
__global__ __launch_bounds__(256) void k_out(
    const float* SS, const float* AOUT,
    const unsigned short* bt_hid, const unsigned short* bt_ctx,
    const float* g_h, const float* b_h, const float* g_c, const float* b_c,
    const float* HG, const float* prev, float* out) {
  __shared__ __align__(16) unsigned short A1[16 * 256];
  __shared__ __align__(16) unsigned short A2[16 * 256];
  __shared__ float C1[16 * 256];
  __shared__ float C2[16 * 256];
  int tid = threadIdx.x, lane = tid & 63, wave = tid >> 6;
  int hi = lane >> 4, lo = lane & 15;
  int r0 = blockIdx.x * 16;
  stage_rows(A1, SS + (size_t)r0 * 256, 16, tid, 256);
  stage_rows(A2, AOUT + (size_t)r0 * 256, 16, tid, 256);
  __syncthreads();
  f32x4 acc1[4], acc2[4];
  #pragma unroll
  for (int ct = 0; ct < 4; ct++) {
    acc1[ct] = f32x4{0.f, 0.f, 0.f, 0.f};
    acc2[ct] = f32x4{0.f, 0.f, 0.f, 0.f};
  }
  #pragma unroll
  for (int kk = 0; kk < 8; kk++) {
    s16x8 a1 = readA(A1, lo, kk, hi);
    s16x8 a2 = readA(A2, lo, kk, hi);
    #pragma unroll
    for (int ct = 0; ct < 4; ct++) {
      int col = wave * 64 + ct * 16 + lo;
      s16x8 b1 = readB(bt_hid, col, kk, hi);
      s16x8 b2 = readB(bt_ctx, col, kk, hi);
      acc1[ct] = mfma16(a1, b1, acc1[ct]);
      acc2[ct] = mfma16(a2, b2, acc2[ct]);
    }
  }
  #pragma unroll
  for (int ct = 0; ct < 4; ct++) {
    int col = wave * 64 + ct * 16 + lo;
    #pragma unroll
    for (int r = 0; r < 4; r++) {
      C1[(hi * 4 + r) * 256 + col] = acc1[ct][r];
      C2[(hi * 4 + r) * 256 + col] = acc2[ct][r];
    }
  }
  __syncthreads();
  #pragma unroll
  for (int mm = 0; mm < 4; mm++) {
    int m = wave * 4 + mm;
    float x1[4], x2[4];
    float s1 = 0.f, q1 = 0.f, s2 = 0.f, q2 = 0.f;
    #pragma unroll
    for (int i = 0; i < 4; i++) {
      x1[i] = C1[m * 256 + lane + 64 * i];
      x2[i] = C2[m * 256 + lane + 64 * i];
      s1 += x1[i]; q1 += x1[i] * x1[i];
      s2 += x2[i]; q2 += x2[i] * x2[i];
    }
    s1 = wredsum(s1); q1 = wredsum(q1);
    s2 = wredsum(s2); q2 = wredsum(q2);
    float mean1 = s1 * (1.0f / 256.0f), var1 = q1 * (1.0f / 256.0f) - mean1 * mean1;
    float mean2 = s2 * (1.0f / 256.0f), var2 = q2 * (1.0f / 256.0f) - mean2 * mean2;
    float rstd1 = rsqrtf(var1 + LN_EPS), rstd2 = rsqrtf(var2 + LN_EPS);
    int gr = r0 + m;
    #pragma unroll
    for (int i = 0; i < 4; i++) {
      int c = lane + 64 * i;
      float y1 = g_h[c] * (x1[i] - mean1) * rstd1 + b_h[c];
      float y2 = g_c[c] * (x2[i] - mean2) * rstd2 + b_c[c];
      float y = fast_tanh(y1 + y2);
      float g = HG[gr * 256 + c];
      float pv = prev[gr * 256 + c];
      out[gr * 256 + c] = (1.0f - g) * y + g * pv;
    }
  }
}

extern "C" void kernel_launch(void* const* d_in, const int* in_sizes, int n_in,
                              void* d_out, int out_size, void* d_ws, size_t ws_size,
                              hipStream_t stream) {
  const float* prev   = (const float*)d_in[0];
  const float* hidden = (const float*)d_in[1];
  const float* enc    = (const float*)d_in[2];
  const float* W_in   = (const float*)d_in[3];
  const float* W_hid  = (const float*)d_in[4];
  const float* W_ctx  = (const float*)d_in[5];
  const float* W_enc  = (const float*)d_in[6];
  const float* W_q    = (const float*)d_in[7];
  const float* v_att  = (const float*)d_in[8];
  const float* g_pre  = (const float*)d_in[9];
  const float* b_pre  = (const float*)d_in[10];
  const float* g_enc  = (const float*)d_in[11];
  const float* b_enc  = (const float*)d_in[12];
  const float* g_h    = (const float*)d_in[13];
  const float* b_h    = (const float*)d_in[14];
  const float* g_c    = (const float*)d_in[15];
  const float* b_c    = (const float*)d_in[16];
  const float* g_q    = (const float*)d_in[17];
  const float* b_q    = (const float*)d_in[18];

  char* ws = (char*)d_ws;
  unsigned short* BT_IN  = (unsigned short*)(ws + 0);        // 768x256 bf16
  unsigned short* BT_Q   = (unsigned short*)(ws + 393216);
  unsigned short* BT_HID = (unsigned short*)(ws + 524288);
  unsigned short* BT_CTX = (unsigned short*)(ws + 655360);
  unsigned short* BT_ENC = (unsigned short*)(ws + 786432);
  float* Z    = (float*)(ws + 917504);    // [4096][256]
  float* HG   = (float*)(ws + 5111808);
  float* XT   = (float*)(ws + 9306112);
  float* SS   = (float*)(ws + 13500416);
  float* Q    = (float*)(ws + 17694720);
  float* AOUT = (float*)(ws + 21889024);

  float* out    = (float*)d_out;          // [4096][256]
  float* finalH = out + 1048576;          // [32][256]
  float* attnO  = out + 1056768;          // [4096][100]

  k_convw <<<448, 256, 0, stream>>>(W_in, W_q, W_hid, W_ctx, W_enc,
                                    BT_IN, BT_Q, BT_HID, BT_CTX, BT_ENC);
  k_preact<<<256, 256, 0, stream>>>(prev, BT_IN, g_pre, b_pre, Z, HG, XT);
  k_scan  <<<32, 256, 0, stream>>>(hidden, Z, XT, SS, finalH);
  k_qproj <<<256, 256, 0, stream>>>(SS, BT_Q, g_q, b_q, Q);
  k_attn  <<<4096, 512, 0, stream>>>(enc, BT_ENC, Q, g_enc, b_enc, v_att, AOUT, attnO);
  k_out   <<<256, 256, 0, stream>>>(SS, AOUT, BT_HID, BT_CTX,
                                    g_h, b_h, g_c, b_c, HG, prev, out);
}